// Round 5
// baseline (696.350 us; speedup 1.0000x reference)
//
#include <hip/hip_runtime.h>
#include <stdint.h>

// CausalHolographicQKV: out = ifft( cumsum_s( unit(F(k)) * unit(F(v)) ) * conj(unit(F(q))) ).real
// Everything stays in the Fourier domain (conjugate-symmetric spectra, packed 1024-float rows).
// GEMM+forward-FFT are chunked over S (4 x 4096 rows) to keep peak workspace at ~190 MiB.

#define NB 4
#define NS 4096
#define ND 1024
#define NROW (NB*NS)        // 16384
#define N3 3072
#define NCHUNK 64
#define SCHUNK 64           // NS / NCHUNK
#define RCH 4096            // rows per GEMM/FFT chunk
#define NCH (NROW / RCH)    // 4 chunks

typedef __attribute__((ext_vector_type(8))) short bf16x8;
typedef __attribute__((ext_vector_type(4))) float f32x4;

__device__ __forceinline__ unsigned short f2bf(float f){
  uint32_t u = __float_as_uint(f);
  uint32_t r = (u + 0x7FFFu + ((u >> 16) & 1u)) >> 16;
  return (unsigned short)r;
}
__device__ __forceinline__ float bf2f(unsigned short h){
  return __uint_as_float(((uint32_t)h) << 16);
}

// LDS bank-conflict swizzle for the FFT arrays (float2 granularity).
// Involution: XORs bits 4-7 into bits 0-3. SW(i + 256c) == SW(i) + 256c.
__device__ __forceinline__ int SW(int i){ return i ^ ((i >> 4) & 15); }

__device__ __forceinline__ void gload16(const void* g, void* l){
  auto gp = reinterpret_cast<const __attribute__((address_space(1))) unsigned int*>(
      reinterpret_cast<uintptr_t>(g));
  auto lp = reinterpret_cast<__attribute__((address_space(3))) unsigned int*>(
      reinterpret_cast<uintptr_t>(l));
  __builtin_amdgcn_global_load_lds(gp, lp, 16, 0, 0);
}

// ---------------- twiddle table: W[j] = exp(-2*pi*i*j/1024) ----------------
__global__ __launch_bounds__(256) void k_twiddle(float2* tw){
  int i = blockIdx.x * 256 + threadIdx.x;
  if (i < 1024){
    double a = -6.283185307179586 * (double)i / 1024.0;
    tw[i] = make_float2((float)cos(a), (float)sin(a));
  }
}

// ---------------- convert W (3 matrices) to bf16 hi/lo + concat bias ----------------
__global__ __launch_bounds__(256) void k_prep_w(const float* __restrict__ Wq, const float* __restrict__ Wk,
                                                const float* __restrict__ Wv, const float* __restrict__ bq,
                                                const float* __restrict__ bk, const float* __restrict__ bv,
                                                unsigned short* __restrict__ Wh, unsigned short* __restrict__ Wl,
                                                float* __restrict__ bcat){
  int idx = blockIdx.x * 256 + threadIdx.x;
  if (idx < N3 * ND){
    int nrow = idx >> 10;
    int d = idx & 1023;
    const float* src = (nrow < 1024) ? Wq : ((nrow < 2048) ? Wk : Wv);
    float w = src[((size_t)(nrow & 1023) << 10) + d];
    unsigned short h = f2bf(w);
    Wh[idx] = h;
    Wl[idx] = f2bf(w - bf2f(h));
  }
  if (idx < N3){
    const float* bs = (idx < 1024) ? bq : ((idx < 2048) ? bk : bv);
    bcat[idx] = bs[idx & 1023];
  }
}

// ---------------- convert x to bf16 hi/lo (vectorized) ----------------
__global__ __launch_bounds__(256) void k_prep_x(const float4* __restrict__ x4,
                                                ushort4* __restrict__ xh4, ushort4* __restrict__ xl4){
  int i = blockIdx.x * 256 + threadIdx.x;   // grid sized exactly: 16777216/4 threads
  float4 v = x4[i];
  ushort4 h, l;
  h.x = f2bf(v.x); l.x = f2bf(v.x - bf2f(h.x));
  h.y = f2bf(v.y); l.y = f2bf(v.y - bf2f(h.y));
  h.z = f2bf(v.z); l.z = f2bf(v.z - bf2f(h.z));
  h.w = f2bf(v.w); l.w = f2bf(v.w - bf2f(h.w));
  xh4[i] = h;
  xl4[i] = l;
}

// ---------------- GEMM (one S-chunk): qkv[r][n] = sum_d x[r][d]*Wcat[n][d] + bcat[n] ----------------
// bf16x3 split interleaved in one K-loop: acc += ah*bh + ah*bl + al*bh.
// 128x128 tile, BK=32, 4 waves (2x2 of 64x64), 48 MFMA per barrier pair.
// m97-class 2-barrier structure (global_load_lds width-16).
// xh/xl/qkv are pre-offset to the chunk base; grid = (RCH/128)*24 = 768 blocks.
__global__ __launch_bounds__(256) void k_gemm(const unsigned short* __restrict__ xh,
                                              const unsigned short* __restrict__ xl,
                                              const unsigned short* __restrict__ Wh,
                                              const unsigned short* __restrict__ Wl,
                                              const float* __restrict__ bcat,
                                              float* __restrict__ qkv){
  __shared__ __attribute__((aligned(16))) unsigned short Ah[128 * 32];
  __shared__ __attribute__((aligned(16))) unsigned short Al[128 * 32];
  __shared__ __attribute__((aligned(16))) unsigned short Bh[128 * 32];
  __shared__ __attribute__((aligned(16))) unsigned short Bl[128 * 32];
  int bid = blockIdx.x;                            // 768 blocks, 768 % 8 == 0
  int swz = (bid & 7) * (768 / 8) + (bid >> 3);    // XCD-bijective swizzle
  int bm = swz / 24;                               // 32 M-tiles (within chunk)
  int bn = swz % 24;                               // 24 N-tiles
  int tid = threadIdx.x;
  int lane = tid & 63, wid = tid >> 6;
  int wr = wid >> 1, wc = wid & 1;

  f32x4 acc[4][4];
#pragma unroll
  for (int i = 0; i < 4; ++i)
#pragma unroll
    for (int j = 0; j < 4; ++j)
      acc[i][j] = (f32x4){0.f, 0.f, 0.f, 0.f};

  int srow = tid >> 2;             // 0..63
  int skoff = (tid & 3) * 8;       // element offset within 32-wide K slab

  size_t ga0 = (size_t)(bm * 128 + srow) * 1024 + skoff;        // A rows 0-63
  size_t ga1 = (size_t)(bm * 128 + 64 + srow) * 1024 + skoff;   // A rows 64-127
  size_t gb0 = (size_t)(bn * 128 + srow) * 1024 + skoff;
  size_t gb1 = (size_t)(bn * 128 + 64 + srow) * 1024 + skoff;

  for (int kt = 0; kt < 32; ++kt){
    int k0 = kt << 5;
    __syncthreads();  // previous compute done before LDS overwrite
    gload16(xh + ga0 + k0, &Ah[tid * 8]);
    gload16(xh + ga1 + k0, &Ah[2048 + tid * 8]);
    gload16(xl + ga0 + k0, &Al[tid * 8]);
    gload16(xl + ga1 + k0, &Al[2048 + tid * 8]);
    gload16(Wh + gb0 + k0, &Bh[tid * 8]);
    gload16(Wh + gb1 + k0, &Bh[2048 + tid * 8]);
    gload16(Wl + gb0 + k0, &Bl[tid * 8]);
    gload16(Wl + gb1 + k0, &Bl[2048 + tid * 8]);
    __syncthreads();  // compiler drains vmcnt(0) before barrier -> tiles ready

    bf16x8 fah[4], fal[4], fbh[4], fbl[4];
    int rbase = (wr * 64 + (lane & 15)) * 32 + (lane >> 4) * 8;
    int cbase = (wc * 64 + (lane & 15)) * 32 + (lane >> 4) * 8;
#pragma unroll
    for (int i = 0; i < 4; ++i){
      fah[i] = *(const bf16x8*)&Ah[rbase + i * 512];
      fal[i] = *(const bf16x8*)&Al[rbase + i * 512];
      fbh[i] = *(const bf16x8*)&Bh[cbase + i * 512];
      fbl[i] = *(const bf16x8*)&Bl[cbase + i * 512];
    }
#pragma unroll
    for (int i = 0; i < 4; ++i)
#pragma unroll
      for (int j = 0; j < 4; ++j){
        acc[i][j] = __builtin_amdgcn_mfma_f32_16x16x32_bf16(fah[i], fbh[j], acc[i][j], 0, 0, 0);
        acc[i][j] = __builtin_amdgcn_mfma_f32_16x16x32_bf16(fah[i], fbl[j], acc[i][j], 0, 0, 0);
        acc[i][j] = __builtin_amdgcn_mfma_f32_16x16x32_bf16(fal[i], fbh[j], acc[i][j], 0, 0, 0);
      }
  }

  int orow = bm * 128 + wr * 64 + (lane >> 4) * 4;
  int ocol = bn * 128 + wc * 64 + (lane & 15);
#pragma unroll
  for (int i = 0; i < 4; ++i){
#pragma unroll
    for (int j = 0; j < 4; ++j){
      int col = ocol + j * 16;
      float bv = bcat[col];
#pragma unroll
      for (int r = 0; r < 4; ++r){
        int row = orow + i * 16 + r;
        qkv[(size_t)row * N3 + col] = acc[i][j][r] + bv;
      }
    }
  }
}

// ---------------- radix-4 Stockham FFT, N=1024, 256 threads, ping-pong LDS ----------------
// All sX/sY/sW indices are SW-swizzled (16-way write-conflict fix, stages 0-1).
// Element i lives at [SW(i)]. Result lands in sY. Caller syncs after filling sX.
__device__ __forceinline__ void fft1024(float2* sX, float2* sY, const float2* sW, int tid){
  float2* src = sX;
  float2* dst = sY;
#pragma unroll
  for (int t = 0; t < 5; ++t){
    int sp = 1 << (2 * t);
    int u = tid;
    int p = u >> (2 * t);
    int us = SW(u);                         // SW(u + 256c) == SW(u) + 256c
    float2 a = src[us], b = src[us + 256], c = src[us + 512], d = src[us + 768];
    float t0x = a.x + c.x, t0y = a.y + c.y;
    float t1x = a.x - c.x, t1y = a.y - c.y;
    float t2x = b.x + d.x, t2y = b.y + d.y;
    float t3x = b.x - d.x, t3y = b.y - d.y;
    float r0x = t0x + t2x, r0y = t0y + t2y;
    float r1x = t1x + t3y, r1y = t1y - t3x;   // t1 - i*t3
    float r2x = t0x - t2x, r2y = t0y - t2y;
    float r3x = t1x - t3y, r3y = t1y + t3x;   // t1 + i*t3
    int tw = p << (2 * t);
    float2 w1 = sW[SW(tw)], w2 = sW[SW(2 * tw)], w3 = sW[SW(3 * tw)];
    int base_o = u + 3 * sp * p;              // q + 4*s*p
    dst[SW(base_o)]          = make_float2(r0x, r0y);
    dst[SW(base_o + sp)]     = make_float2(r1x * w1.x - r1y * w1.y, r1x * w1.y + r1y * w1.x);
    dst[SW(base_o + 2 * sp)] = make_float2(r2x * w2.x - r2y * w2.y, r2x * w2.y + r2y * w2.x);
    dst[SW(base_o + 3 * sp)] = make_float2(r3x * w3.x - r3y * w3.y, r3x * w3.y + r3y * w3.x);
    __syncthreads();
    float2* tmp = src; src = dst; dst = tmp;
  }
}

// ---------------- forward (one S-chunk): per row FFT(q) -> unit -> packed Fq ;
// FFT(k+iv) -> unit both -> product -> packed Fxk
// packed layout (1024 floats): slot[d]=Re(F[d]) for d=0..512 ; slot[512+d]=Im(F[d]) for d=1..511
// qkv/Fq/Fxk are pre-offset to the chunk base; grid = RCH blocks.
__global__ __launch_bounds__(256) void k_fft_fwd(const float* __restrict__ qkv,
                                                 float* __restrict__ Fq, float* __restrict__ Fxk,
                                                 const float2* __restrict__ twg){
  __shared__ __attribute__((aligned(16))) float2 sX[1024];
  __shared__ __attribute__((aligned(16))) float2 sY[1024];
  __shared__ __attribute__((aligned(16))) float2 sW[1024];
  int tid = threadIdx.x;
  size_t row = blockIdx.x;
  const float* qr = qkv + row * N3;

#pragma unroll
  for (int i = tid; i < 1024; i += 256) sW[SW(i)] = twg[i];

  // ---- Q ----
#pragma unroll
  for (int i = tid; i < 1024; i += 256) sX[SW(i)] = make_float2(qr[i], 0.f);
  __syncthreads();
  fft1024(sX, sY, sW, tid);
  float* pk = (float*)sX;  // sX dead after fft (last stage wrote sY); raw linear scratch
  for (int d = tid; d <= 512; d += 256){
    float2 F = sY[SW(d)];
    float sc = 1.f / (sqrtf(F.x * F.x + F.y * F.y) + 1e-8f);
    pk[d] = F.x * sc;
    if (d != 0 && d != 512) pk[512 + d] = F.y * sc;
  }
  __syncthreads();
  ((float4*)(Fq + row * 1024))[tid] = ((const float4*)pk)[tid];
  __syncthreads();  // all LDS reads for the store drained before sX reuse

  // ---- K + i*V ----
  const float* kr = qr + 1024;
  const float* vr = qr + 2048;
#pragma unroll
  for (int i = tid; i < 1024; i += 256) sX[SW(i)] = make_float2(kr[i], vr[i]);
  __syncthreads();
  fft1024(sX, sY, sW, tid);
  pk = (float*)sX;
  for (int d = tid; d <= 512; d += 256){
    float2 Fd = sY[SW(d)];
    float2 Fr = sY[SW((1024 - d) & 1023)];
    // untangle: Fk = (F[d]+conj(F[N-d]))/2 ; Fv = -i*(F[d]-conj(F[N-d]))/2
    float kre = 0.5f * (Fd.x + Fr.x), kim = 0.5f * (Fd.y - Fr.y);
    float vre = 0.5f * (Fd.y + Fr.y), vim = 0.5f * (Fr.x - Fd.x);
    float s1 = 1.f / (sqrtf(kre * kre + kim * kim) + 1e-8f);
    float s2 = 1.f / (sqrtf(vre * vre + vim * vim) + 1e-8f);
    kre *= s1; kim *= s1; vre *= s2; vim *= s2;
    float pre = kre * vre - kim * vim;
    float pim = kre * vim + kim * vre;
    pk[d] = pre;
    if (d != 0 && d != 512) pk[512 + d] = pim;
  }
  __syncthreads();
  ((float4*)(Fxk + row * 1024))[tid] = ((const float4*)pk)[tid];
}

// ---------------- cumsum pass A: in-chunk inclusive prefix (in place) + chunk totals ----------------
__global__ __launch_bounds__(256) void k_scan_local(float* __restrict__ buf, float* __restrict__ ctot){
  int sc = blockIdx.x;      // 0..63
  int dblk = blockIdx.y;    // 0..3
  int b = blockIdx.z;       // 0..3
  int d = dblk * 256 + threadIdx.x;
  size_t base = ((size_t)b * NS + (size_t)sc * SCHUNK) * 1024 + d;
  float run = 0.f;
  for (int i = 0; i < SCHUNK; ++i){
    float v = buf[base + (size_t)i * 1024];
    run += v;
    buf[base + (size_t)i * 1024] = run;
  }
  ctot[((size_t)b * NCHUNK + sc) * 1024 + d] = run;
}

// ---------------- cumsum pass B: exclusive scan of chunk totals ----------------
__global__ __launch_bounds__(256) void k_scan_off(const float* __restrict__ ctot, float* __restrict__ coff){
  int b = blockIdx.x >> 2;
  int dblk = blockIdx.x & 3;
  int d = dblk * 256 + threadIdx.x;
  float run = 0.f;
  for (int c = 0; c < NCHUNK; ++c){
    size_t idx = ((size_t)b * NCHUNK + c) * 1024 + d;
    float t = ctot[idx];
    coff[idx] = run;
    run += t;
  }
}

// ---------------- final: H = (Sloc+off) * conj(Fq) ; out = Re(FFT(conj(H)))/1024 ----------------
__global__ __launch_bounds__(256) void k_fft_inv(const float* __restrict__ Sloc, const float* __restrict__ coff,
                                                 const float* __restrict__ Fq, float* __restrict__ out,
                                                 const float2* __restrict__ twg){
  __shared__ __attribute__((aligned(16))) float2 sX[1024];
  __shared__ __attribute__((aligned(16))) float2 sY[1024];
  __shared__ __attribute__((aligned(16))) float2 sW[1024];
  int tid = threadIdx.x;
  size_t row = blockIdx.x;
  int b = (int)(row >> 12);
  int s = (int)(row & 4095);
  int ch = s >> 6;
  float* SP = (float*)sY;   // raw linear scratch in sY region (2048 floats exactly)
  float* QP = SP + 1024;
  size_t obase = ((size_t)b * NCHUNK + ch) * 1024;
#pragma unroll
  for (int i = tid; i < 1024; i += 256){
    sW[SW(i)] = twg[i];
    SP[i] = Sloc[row * 1024 + i] + coff[obase + i];
    QP[i] = Fq[row * 1024 + i];
  }
  __syncthreads();
  for (int d = tid; d <= 512; d += 256){
    bool edge = (d == 0 || d == 512);
    float sre = SP[d], sim = edge ? 0.f : SP[512 + d];
    float qre = QP[d], qim = edge ? 0.f : QP[512 + d];
    float hre = sre * qre + sim * qim;     // H = S * conj(Q)
    float him = sim * qre - sre * qim;
    sX[SW(d)] = make_float2(hre, -him);    // store conj(H)
    if (!edge) sX[SW(1024 - d)] = make_float2(hre, him);  // conj(H[N-d]) = H[d]
  }
  __syncthreads();
  fft1024(sX, sY, sW, tid);
  const float inv = 1.f / 1024.f;
  for (int i = tid; i < 1024; i += 256)
    out[row * 1024 + i] = sY[SW(i)].x * inv;
}

extern "C" void kernel_launch(void* const* d_in, const int* in_sizes, int n_in,
                              void* d_out, int out_size, void* d_ws, size_t ws_size,
                              hipStream_t stream){
  const float* x  = (const float*)d_in[0];
  const float* Wq = (const float*)d_in[1];
  const float* bq = (const float*)d_in[2];
  const float* Wk = (const float*)d_in[3];
  const float* bk = (const float*)d_in[4];
  const float* Wv = (const float*)d_in[5];
  const float* bv = (const float*)d_in[6];
  float* out = (float*)d_out;

  char* ws = (char*)d_ws;
  size_t off = 0;
  auto alloc = [&](size_t bytes) -> void* {
    void* p = ws + off;
    off += (bytes + 255) & ~(size_t)255;
    return p;
  };
  // Peak workspace: 48+32+32+6+6+64+2 MiB ~= 190.1 MiB (fits a 192 MiB ws; round-3's
  // 283 MiB layout crossed the 256 MiB line exactly at Wh -> suspected OOB abort).
  float*          qkvc = (float*)alloc((size_t)RCH * N3 * 4);           // 48 MiB (chunk-reused)
  unsigned short* xh   = (unsigned short*)alloc((size_t)NROW * ND * 2); // 32 MiB
  unsigned short* xl   = (unsigned short*)alloc((size_t)NROW * ND * 2); // 32 MiB
  unsigned short* Wh   = (unsigned short*)alloc((size_t)N3 * ND * 2);   // 6 MiB
  unsigned short* Wl   = (unsigned short*)alloc((size_t)N3 * ND * 2);   // 6 MiB
  float*          Fq   = (float*)alloc((size_t)NROW * ND * 4);          // 64 MiB
  float*          bcat = (float*)alloc(N3 * 4);
  float2*         tw   = (float2*)alloc(1024 * 8);
  float*          ctot = (float*)alloc((size_t)NB * NCHUNK * 1024 * 4); // 1 MiB
  float*          coff = (float*)alloc((size_t)NB * NCHUNK * 1024 * 4); // 1 MiB
  // Fxk lives in d_out (fully overwritten by k_fft_fwd; scanned in place; k_fft_inv is per-row in-place)
  float* Fxk = out;

  k_twiddle<<<4, 256, 0, stream>>>(tw);
  k_prep_w<<<(N3 * ND + 255) / 256, 256, 0, stream>>>(Wq, Wk, Wv, bq, bk, bv, Wh, Wl, bcat);
  k_prep_x<<<NROW * ND / 4 / 256, 256, 0, stream>>>((const float4*)x, (ushort4*)xh, (ushort4*)xl);

  for (int c = 0; c < NCH; ++c){
    size_t rb = (size_t)c * RCH;
    k_gemm<<<(RCH / 128) * (N3 / 128), 256, 0, stream>>>(
        xh + rb * ND, xl + rb * ND, Wh, Wl, bcat, qkvc);
    k_fft_fwd<<<RCH, 256, 0, stream>>>(qkvc, Fq + rb * ND, Fxk + rb * ND, tw);
  }

  k_scan_local<<<dim3(NCHUNK, 4, NB), 256, 0, stream>>>(Fxk, ctot);
  k_scan_off<<<NB * 4, 256, 0, stream>>>(ctot, coff);
  k_fft_inv<<<NROW, 256, 0, stream>>>(Fxk, coff, Fq, out, tw);
}

// Round 7
// 487.820 us; speedup vs baseline: 1.4275x; 1.4275x over previous
//
#include <hip/hip_runtime.h>
#include <stdint.h>

// CausalHolographicQKV: out = ifft( cumsum_s( unit(F(k)) * unit(F(v)) ) * conj(unit(F(q))) ).real
// Everything stays in the Fourier domain (conjugate-symmetric spectra, packed 1024-float rows).
// GEMM+forward-FFT chunked over S (4 x 4096 rows); GEMM is single-product fp16 (11-bit mantissa).

#define NB 4
#define NS 4096
#define ND 1024
#define NROW (NB*NS)        // 16384
#define N3 3072
#define NCHUNK 64
#define SCHUNK 64           // NS / NCHUNK
#define RCH 4096            // rows per GEMM/FFT chunk
#define NCH (NROW / RCH)    // 4 chunks

typedef __attribute__((ext_vector_type(8))) _Float16 f16x8;
typedef __attribute__((ext_vector_type(4))) _Float16 f16x4;
typedef __attribute__((ext_vector_type(4))) float f32x4;

// LDS bank-conflict swizzle for the FFT arrays (float2 granularity).
// Involution: XORs bits 4-7 into bits 0-3. SW(i + 256c) == SW(i) + 256c.
__device__ __forceinline__ int SW(int i){ return i ^ ((i >> 4) & 15); }

__device__ __forceinline__ void gload16(const void* g, void* l){
  auto gp = reinterpret_cast<const __attribute__((address_space(1))) unsigned int*>(
      reinterpret_cast<uintptr_t>(g));
  auto lp = reinterpret_cast<__attribute__((address_space(3))) unsigned int*>(
      reinterpret_cast<uintptr_t>(l));
  __builtin_amdgcn_global_load_lds(gp, lp, 16, 0, 0);
}

// ---------------- twiddle table: W[j] = exp(-2*pi*i*j/1024) ----------------
__global__ __launch_bounds__(256) void k_twiddle(float2* tw){
  int i = blockIdx.x * 256 + threadIdx.x;
  if (i < 1024){
    double a = -6.283185307179586 * (double)i / 1024.0;
    tw[i] = make_float2((float)cos(a), (float)sin(a));
  }
}

// ---------------- convert W (3 matrices) to fp16 + concat bias ----------------
__global__ __launch_bounds__(256) void k_prep_w(const float* __restrict__ Wq, const float* __restrict__ Wk,
                                                const float* __restrict__ Wv, const float* __restrict__ bq,
                                                const float* __restrict__ bk, const float* __restrict__ bv,
                                                _Float16* __restrict__ Wf, float* __restrict__ bcat){
  int idx = blockIdx.x * 256 + threadIdx.x;
  if (idx < N3 * ND){
    int nrow = idx >> 10;
    int d = idx & 1023;
    const float* src = (nrow < 1024) ? Wq : ((nrow < 2048) ? Wk : Wv);
    Wf[idx] = (_Float16)src[((size_t)(nrow & 1023) << 10) + d];
  }
  if (idx < N3){
    const float* bs = (idx < 1024) ? bq : ((idx < 2048) ? bk : bv);
    bcat[idx] = bs[idx & 1023];
  }
}

// ---------------- convert x to fp16 (vectorized) ----------------
__global__ __launch_bounds__(256) void k_prep_x(const float4* __restrict__ x4,
                                                f16x4* __restrict__ xf4){
  int i = blockIdx.x * 256 + threadIdx.x;   // grid sized exactly: 16777216/4 threads
  float4 v = x4[i];
  f16x4 h;
  h[0] = (_Float16)v.x; h[1] = (_Float16)v.y;
  h[2] = (_Float16)v.z; h[3] = (_Float16)v.w;
  xf4[i] = h;
}

// ---------------- GEMM (one S-chunk): qkv[r][n] = sum_d x[r][d]*Wcat[n][d] + bcat[n] ----------------
// Single fp16 product. 128x128 tile, BK=32, 4 waves (2x2 of 64x64), 16 MFMA per barrier pair.
// m97-class 2-barrier structure (global_load_lds width-16). LDS 16 KB.
// xf/qkv pre-offset to the chunk base; grid = (RCH/128)*24 = 768 blocks.
__global__ __launch_bounds__(256) void k_gemm(const _Float16* __restrict__ xf,
                                              const _Float16* __restrict__ Wf,
                                              const float* __restrict__ bcat,
                                              float* __restrict__ qkv){
  __shared__ __attribute__((aligned(16))) _Float16 As[128 * 32];
  __shared__ __attribute__((aligned(16))) _Float16 Bs[128 * 32];
  int bid = blockIdx.x;                            // 768 blocks, 768 % 8 == 0
  int swz = (bid & 7) * (768 / 8) + (bid >> 3);    // XCD-bijective swizzle
  int bm = swz / 24;                               // 32 M-tiles (within chunk)
  int bn = swz % 24;                               // 24 N-tiles
  int tid = threadIdx.x;
  int lane = tid & 63, wid = tid >> 6;
  int wr = wid >> 1, wc = wid & 1;

  f32x4 acc[4][4];
#pragma unroll
  for (int i = 0; i < 4; ++i)
#pragma unroll
    for (int j = 0; j < 4; ++j)
      acc[i][j] = (f32x4){0.f, 0.f, 0.f, 0.f};

  int srow = tid >> 2;             // 0..63
  int skoff = (tid & 3) * 8;       // element offset within 32-wide K slab

  size_t ga0 = (size_t)(bm * 128 + srow) * 1024 + skoff;        // A rows 0-63
  size_t ga1 = (size_t)(bm * 128 + 64 + srow) * 1024 + skoff;   // A rows 64-127
  size_t gb0 = (size_t)(bn * 128 + srow) * 1024 + skoff;
  size_t gb1 = (size_t)(bn * 128 + 64 + srow) * 1024 + skoff;

  for (int kt = 0; kt < 32; ++kt){
    int k0 = kt << 5;
    __syncthreads();  // previous compute done before LDS overwrite
    gload16(xf + ga0 + k0, &As[tid * 8]);
    gload16(xf + ga1 + k0, &As[2048 + tid * 8]);
    gload16(Wf + gb0 + k0, &Bs[tid * 8]);
    gload16(Wf + gb1 + k0, &Bs[2048 + tid * 8]);
    __syncthreads();  // compiler drains vmcnt(0) before barrier -> tiles ready

    f16x8 fa[4], fb[4];
    int rbase = (wr * 64 + (lane & 15)) * 32 + (lane >> 4) * 8;
    int cbase = (wc * 64 + (lane & 15)) * 32 + (lane >> 4) * 8;
#pragma unroll
    for (int i = 0; i < 4; ++i){
      fa[i] = *(const f16x8*)&As[rbase + i * 512];
      fb[i] = *(const f16x8*)&Bs[cbase + i * 512];
    }
#pragma unroll
    for (int i = 0; i < 4; ++i)
#pragma unroll
      for (int j = 0; j < 4; ++j)
        acc[i][j] = __builtin_amdgcn_mfma_f32_16x16x32_f16(fa[i], fb[j], acc[i][j], 0, 0, 0);
  }

  int orow = bm * 128 + wr * 64 + (lane >> 4) * 4;
  int ocol = bn * 128 + wc * 64 + (lane & 15);
#pragma unroll
  for (int i = 0; i < 4; ++i){
#pragma unroll
    for (int j = 0; j < 4; ++j){
      int col = ocol + j * 16;
      float bv = bcat[col];
#pragma unroll
      for (int r = 0; r < 4; ++r){
        int row = orow + i * 16 + r;
        qkv[(size_t)row * N3 + col] = acc[i][j][r] + bv;
      }
    }
  }
}

// ---------------- radix-4 Stockham FFT, N=1024, 256 threads, ping-pong LDS ----------------
// All sX/sY/sW indices are SW-swizzled (16-way write-conflict fix, stages 0-1).
// Element i lives at [SW(i)]. Result lands in sY. Caller syncs after filling sX.
__device__ __forceinline__ void fft1024(float2* sX, float2* sY, const float2* sW, int tid){
  float2* src = sX;
  float2* dst = sY;
#pragma unroll
  for (int t = 0; t < 5; ++t){
    int sp = 1 << (2 * t);
    int u = tid;
    int p = u >> (2 * t);
    int us = SW(u);                         // SW(u + 256c) == SW(u) + 256c
    float2 a = src[us], b = src[us + 256], c = src[us + 512], d = src[us + 768];
    float t0x = a.x + c.x, t0y = a.y + c.y;
    float t1x = a.x - c.x, t1y = a.y - c.y;
    float t2x = b.x + d.x, t2y = b.y + d.y;
    float t3x = b.x - d.x, t3y = b.y - d.y;
    float r0x = t0x + t2x, r0y = t0y + t2y;
    float r1x = t1x + t3y, r1y = t1y - t3x;   // t1 - i*t3
    float r2x = t0x - t2x, r2y = t0y - t2y;
    float r3x = t1x - t3y, r3y = t1y + t3x;   // t1 + i*t3
    int tw = p << (2 * t);
    float2 w1 = sW[SW(tw)], w2 = sW[SW(2 * tw)], w3 = sW[SW(3 * tw)];
    int base_o = u + 3 * sp * p;              // q + 4*s*p
    dst[SW(base_o)]          = make_float2(r0x, r0y);
    dst[SW(base_o + sp)]     = make_float2(r1x * w1.x - r1y * w1.y, r1x * w1.y + r1y * w1.x);
    dst[SW(base_o + 2 * sp)] = make_float2(r2x * w2.x - r2y * w2.y, r2x * w2.y + r2y * w2.x);
    dst[SW(base_o + 3 * sp)] = make_float2(r3x * w3.x - r3y * w3.y, r3x * w3.y + r3y * w3.x);
    __syncthreads();
    float2* tmp = src; src = dst; dst = tmp;
  }
}

// ---------------- forward (one S-chunk): per row FFT(q) -> unit -> packed Fq ;
// FFT(k+iv) -> unit both -> product -> packed Fxk
// packed layout (1024 floats): slot[d]=Re(F[d]) for d=0..512 ; slot[512+d]=Im(F[d]) for d=1..511
// qkv/Fq/Fxk pre-offset to the chunk base; grid = RCH blocks.
__global__ __launch_bounds__(256) void k_fft_fwd(const float* __restrict__ qkv,
                                                 float* __restrict__ Fq, float* __restrict__ Fxk,
                                                 const float2* __restrict__ twg){
  __shared__ __attribute__((aligned(16))) float2 sX[1024];
  __shared__ __attribute__((aligned(16))) float2 sY[1024];
  __shared__ __attribute__((aligned(16))) float2 sW[1024];
  int tid = threadIdx.x;
  size_t row = blockIdx.x;
  const float* qr = qkv + row * N3;

#pragma unroll
  for (int i = tid; i < 1024; i += 256) sW[SW(i)] = twg[i];

  // ---- Q ----
#pragma unroll
  for (int i = tid; i < 1024; i += 256) sX[SW(i)] = make_float2(qr[i], 0.f);
  __syncthreads();
  fft1024(sX, sY, sW, tid);
  float* pk = (float*)sX;  // sX dead after fft (last stage wrote sY); raw linear scratch
  for (int d = tid; d <= 512; d += 256){
    float2 F = sY[SW(d)];
    float sc = 1.f / (sqrtf(F.x * F.x + F.y * F.y) + 1e-8f);
    pk[d] = F.x * sc;
    if (d != 0 && d != 512) pk[512 + d] = F.y * sc;
  }
  __syncthreads();
  ((float4*)(Fq + row * 1024))[tid] = ((const float4*)pk)[tid];
  __syncthreads();  // all LDS reads for the store drained before sX reuse

  // ---- K + i*V ----
  const float* kr = qr + 1024;
  const float* vr = qr + 2048;
#pragma unroll
  for (int i = tid; i < 1024; i += 256) sX[SW(i)] = make_float2(kr[i], vr[i]);
  __syncthreads();
  fft1024(sX, sY, sW, tid);
  pk = (float*)sX;
  for (int d = tid; d <= 512; d += 256){
    float2 Fd = sY[SW(d)];
    float2 Fr = sY[SW((1024 - d) & 1023)];
    // untangle: Fk = (F[d]+conj(F[N-d]))/2 ; Fv = -i*(F[d]-conj(F[N-d]))/2
    float kre = 0.5f * (Fd.x + Fr.x), kim = 0.5f * (Fd.y - Fr.y);
    float vre = 0.5f * (Fd.y + Fr.y), vim = 0.5f * (Fr.x - Fd.x);
    float s1 = 1.f / (sqrtf(kre * kre + kim * kim) + 1e-8f);
    float s2 = 1.f / (sqrtf(vre * vre + vim * vim) + 1e-8f);
    kre *= s1; kim *= s1; vre *= s2; vim *= s2;
    float pre = kre * vre - kim * vim;
    float pim = kre * vim + kim * vre;
    pk[d] = pre;
    if (d != 0 && d != 512) pk[512 + d] = pim;
  }
  __syncthreads();
  ((float4*)(Fxk + row * 1024))[tid] = ((const float4*)pk)[tid];
}

// ---------------- cumsum pass A: in-chunk inclusive prefix (in place) + chunk totals ----------------
__global__ __launch_bounds__(256) void k_scan_local(float* __restrict__ buf, float* __restrict__ ctot){
  int sc = blockIdx.x;      // 0..63
  int dblk = blockIdx.y;    // 0..3
  int b = blockIdx.z;       // 0..3
  int d = dblk * 256 + threadIdx.x;
  size_t base = ((size_t)b * NS + (size_t)sc * SCHUNK) * 1024 + d;
  float run = 0.f;
  for (int i = 0; i < SCHUNK; ++i){
    float v = buf[base + (size_t)i * 1024];
    run += v;
    buf[base + (size_t)i * 1024] = run;
  }
  ctot[((size_t)b * NCHUNK + sc) * 1024 + d] = run;
}

// ---------------- cumsum pass B: exclusive scan of chunk totals ----------------
__global__ __launch_bounds__(256) void k_scan_off(const float* __restrict__ ctot, float* __restrict__ coff){
  int b = blockIdx.x >> 2;
  int dblk = blockIdx.x & 3;
  int d = dblk * 256 + threadIdx.x;
  float run = 0.f;
  for (int c = 0; c < NCHUNK; ++c){
    size_t idx = ((size_t)b * NCHUNK + c) * 1024 + d;
    float t = ctot[idx];
    coff[idx] = run;
    run += t;
  }
}

// ---------------- final: H = (Sloc+off) * conj(Fq) ; out = Re(FFT(conj(H)))/1024 ----------------
__global__ __launch_bounds__(256) void k_fft_inv(const float* __restrict__ Sloc, const float* __restrict__ coff,
                                                 const float* __restrict__ Fq, float* __restrict__ out,
                                                 const float2* __restrict__ twg){
  __shared__ __attribute__((aligned(16))) float2 sX[1024];
  __shared__ __attribute__((aligned(16))) float2 sY[1024];
  __shared__ __attribute__((aligned(16))) float2 sW[1024];
  int tid = threadIdx.x;
  size_t row = blockIdx.x;
  int b = (int)(row >> 12);
  int s = (int)(row & 4095);
  int ch = s >> 6;
  float* SP = (float*)sY;   // raw linear scratch in sY region (2048 floats exactly)
  float* QP = SP + 1024;
  size_t obase = ((size_t)b * NCHUNK + ch) * 1024;
#pragma unroll
  for (int i = tid; i < 1024; i += 256){
    sW[SW(i)] = twg[i];
    SP[i] = Sloc[row * 1024 + i] + coff[obase + i];
    QP[i] = Fq[row * 1024 + i];
  }
  __syncthreads();
  for (int d = tid; d <= 512; d += 256){
    bool edge = (d == 0 || d == 512);
    float sre = SP[d], sim = edge ? 0.f : SP[512 + d];
    float qre = QP[d], qim = edge ? 0.f : QP[512 + d];
    float hre = sre * qre + sim * qim;     // H = S * conj(Q)
    float him = sim * qre - sre * qim;
    sX[SW(d)] = make_float2(hre, -him);    // store conj(H)
    if (!edge) sX[SW(1024 - d)] = make_float2(hre, him);  // conj(H[N-d]) = H[d]
  }
  __syncthreads();
  fft1024(sX, sY, sW, tid);
  const float inv = 1.f / 1024.f;
  for (int i = tid; i < 1024; i += 256)
    out[row * 1024 + i] = sY[SW(i)].x * inv;
}

extern "C" void kernel_launch(void* const* d_in, const int* in_sizes, int n_in,
                              void* d_out, int out_size, void* d_ws, size_t ws_size,
                              hipStream_t stream){
  const float* x  = (const float*)d_in[0];
  const float* Wq = (const float*)d_in[1];
  const float* bq = (const float*)d_in[2];
  const float* Wk = (const float*)d_in[3];
  const float* bk = (const float*)d_in[4];
  const float* Wv = (const float*)d_in[5];
  const float* bv = (const float*)d_in[6];
  float* out = (float*)d_out;

  char* ws = (char*)d_ws;
  size_t off = 0;
  auto alloc = [&](size_t bytes) -> void* {
    void* p = ws + off;
    off += (bytes + 255) & ~(size_t)255;
    return p;
  };
  // Peak workspace: 48+32+6+64+2 MiB ~= 152 MiB.
  float*     qkvc = (float*)alloc((size_t)RCH * N3 * 4);           // 48 MiB (chunk-reused)
  _Float16*  xf   = (_Float16*)alloc((size_t)NROW * ND * 2);       // 32 MiB
  _Float16*  Wf   = (_Float16*)alloc((size_t)N3 * ND * 2);         // 6 MiB
  float*     Fq   = (float*)alloc((size_t)NROW * ND * 4);          // 64 MiB
  float*     bcat = (float*)alloc(N3 * 4);
  float2*    tw   = (float2*)alloc(1024 * 8);
  float*     ctot = (float*)alloc((size_t)NB * NCHUNK * 1024 * 4); // 1 MiB
  float*     coff = (float*)alloc((size_t)NB * NCHUNK * 1024 * 4); // 1 MiB
  // Fxk lives in d_out (fully overwritten by k_fft_fwd; scanned in place; k_fft_inv is per-row in-place)
  float* Fxk = out;

  k_twiddle<<<4, 256, 0, stream>>>(tw);
  k_prep_w<<<(N3 * ND + 255) / 256, 256, 0, stream>>>(Wq, Wk, Wv, bq, bk, bv, Wf, bcat);
  k_prep_x<<<NROW * ND / 4 / 256, 256, 0, stream>>>((const float4*)x, (f16x4*)xf);

  for (int c = 0; c < NCH; ++c){
    size_t rb = (size_t)c * RCH;
    k_gemm<<<(RCH / 128) * (N3 / 128), 256, 0, stream>>>(
        xf + rb * ND, Wf, bcat, qkvc);
    k_fft_fwd<<<RCH, 256, 0, stream>>>(qkvc, Fq + rb * ND, Fxk + rb * ND, tw);
  }

  k_scan_local<<<dim3(NCHUNK, 4, NB), 256, 0, stream>>>(Fxk, ctot);
  k_scan_off<<<NB * 4, 256, 0, stream>>>(ctot, coff);
  k_fft_inv<<<NROW, 256, 0, stream>>>(Fxk, coff, Fq, out, tw);
}